// Round 1
// baseline (87.471 us; speedup 1.0000x reference)
//
#include <hip/hip_runtime.h>

#define IN_DIM 4096
#define N_SOMA 16384
#define N_NEURONS 1024
#define BATCH 256
#define NEG_SLOPE 0.1f

// ---------------------------------------------------------------------------
// Kernel 1: transpose x [BATCH][IN_DIM] -> xT [IN_DIM][BATCH]
// 64x64 tiles via LDS (padded to kill bank conflicts).
// ---------------------------------------------------------------------------
__global__ __launch_bounds__(256) void transpose_x_kernel(
    const float* __restrict__ x, float* __restrict__ xT) {
    __shared__ float tile[64][65];
    const int i0 = blockIdx.x * 64;   // input-dim tile origin
    const int b0 = blockIdx.y * 64;   // batch tile origin
    const int lane = threadIdx.x & 63;
    const int grp  = threadIdx.x >> 6;  // 0..3

#pragma unroll
    for (int r = 0; r < 16; ++r) {
        const int b_local = grp * 16 + r;
        tile[b_local][lane] = x[(size_t)(b0 + b_local) * IN_DIM + i0 + lane];
    }
    __syncthreads();
#pragma unroll
    for (int r = 0; r < 16; ++r) {
        const int i_local = grp * 16 + r;
        xT[(size_t)(i0 + i_local) * BATCH + b0 + lane] = tile[lane][i_local];
    }
}

// ---------------------------------------------------------------------------
// Kernel 2: sparse dendrite stage.
// One 256-thread block per soma row d.
//  Phase 1: stream W[d][:] (4096 f32) coalesced as float4, compact the
//           (index, weight) nonzeros into LDS with a deterministic prefix
//           scan (exactly 32 nonzeros per row by construction).
//  Phase 2: thread t = batch b; acc over nonzeros with coalesced xT reads.
// Output: dendT [N_SOMA][BATCH] (transposed layout for the soma stage).
// ---------------------------------------------------------------------------
__global__ __launch_bounds__(256) void dendrite_kernel(
    const float* __restrict__ W, const float* __restrict__ bias,
    const float* __restrict__ xT, float* __restrict__ dendT) {
    const int d = blockIdx.x;
    const int t = threadIdx.x;
    const float4* row4 = reinterpret_cast<const float4*>(W + (size_t)d * IN_DIM);

    // 4096 floats = 1024 float4; 256 threads -> 4 float4 each, coalesced.
    float4 v[4];
#pragma unroll
    for (int k = 0; k < 4; ++k) v[k] = row4[k * 256 + t];

    int cnt = 0;
#pragma unroll
    for (int k = 0; k < 4; ++k) {
        cnt += (v[k].x != 0.f) + (v[k].y != 0.f) + (v[k].z != 0.f) + (v[k].w != 0.f);
    }

    __shared__ int   s_scan[256];
    __shared__ int   s_idx[64];
    __shared__ float s_w[64];

    s_scan[t] = cnt;
    __syncthreads();
    // Hillis-Steele inclusive scan over 256 counts (deterministic compaction
    // order -> bitwise-reproducible accumulation, no atomics).
#pragma unroll
    for (int off = 1; off < 256; off <<= 1) {
        const int val = (t >= off) ? s_scan[t - off] : 0;
        __syncthreads();
        s_scan[t] += val;
        __syncthreads();
    }
    int total = s_scan[255];
    int pos = s_scan[t] - cnt;  // exclusive prefix

    float vals[16];
#pragma unroll
    for (int k = 0; k < 4; ++k) {
        vals[k * 4 + 0] = v[k].x; vals[k * 4 + 1] = v[k].y;
        vals[k * 4 + 2] = v[k].z; vals[k * 4 + 3] = v[k].w;
    }
#pragma unroll
    for (int k = 0; k < 4; ++k) {
#pragma unroll
        for (int c = 0; c < 4; ++c) {
            const float w = vals[k * 4 + c];
            if (w != 0.f) {
                if (pos < 64) {
                    s_idx[pos] = (k * 256 + t) * 4 + c;
                    s_w[pos] = w;
                }
                ++pos;
            }
        }
    }
    __syncthreads();
    if (total > 64) total = 64;  // defensive; construction guarantees 32

    float acc = bias[d];
    for (int j = 0; j < total; ++j) {
        acc = fmaf(s_w[j], xT[(size_t)s_idx[j] * BATCH + t], acc);
    }
    acc = (acc >= 0.f) ? acc : NEG_SLOPE * acc;
    dendT[(size_t)d * BATCH + t] = acc;
}

// ---------------------------------------------------------------------------
// Kernel 3: block-diagonal soma stage.
// Block = 16 neurons x 64 batch. Stage the 16x16 soma_W diagonal block in
// LDS. Each thread: 4 neurons x 1 batch, 64 FMAs, float4 output write.
// ---------------------------------------------------------------------------
__global__ __launch_bounds__(256) void soma_kernel(
    const float* __restrict__ sW, const float* __restrict__ sb,
    const float* __restrict__ dendT, float* __restrict__ out) {
    const int ng = blockIdx.x;          // neuron group of 16
    const int bg = blockIdx.y;          // batch group of 64
    const int lane = threadIdx.x & 63;
    const int wid  = threadIdx.x >> 6;  // 0..3 -> 4 neurons each
    const int b = bg * 64 + lane;

    __shared__ float s_sw[16][16];
    {
        const int n_local = threadIdx.x >> 4;
        const int j = threadIdx.x & 15;
        const int n = ng * 16 + n_local;
        s_sw[n_local][j] = sW[(size_t)n * N_SOMA + n * 16 + j];
    }
    __syncthreads();

    float res[4];
#pragma unroll
    for (int nn = 0; nn < 4; ++nn) {
        const int n_local = wid * 4 + nn;
        const int n = ng * 16 + n_local;
        float acc = sb[n];
#pragma unroll
        for (int j = 0; j < 16; ++j) {
            const int dd = n * 16 + j;
            acc = fmaf(s_sw[n_local][j], dendT[(size_t)dd * BATCH + b], acc);
        }
        res[nn] = (acc >= 0.f) ? acc : NEG_SLOPE * acc;
    }
    float4 o = make_float4(res[0], res[1], res[2], res[3]);
    *reinterpret_cast<float4*>(out + (size_t)b * N_NEURONS + ng * 16 + wid * 4) = o;
}

// ---------------------------------------------------------------------------
extern "C" void kernel_launch(void* const* d_in, const int* in_sizes, int n_in,
                              void* d_out, int out_size, void* d_ws, size_t ws_size,
                              hipStream_t stream) {
    const float* x  = (const float*)d_in[0];  // [256][4096]
    const float* dW = (const float*)d_in[1];  // [16384][4096] (pre-masked)
    const float* db = (const float*)d_in[2];  // [16384]
    const float* sW = (const float*)d_in[3];  // [1024][16384] (pre-masked)
    const float* sb = (const float*)d_in[4];  // [1024]
    // d_in[5] = dendrite_mask, d_in[6] = soma_mask: redundant (W pre-masked).
    float* out = (float*)d_out;               // [256][1024]

    float* xT    = (float*)d_ws;                          // [4096][256]  4 MB
    float* dendT = xT + (size_t)IN_DIM * BATCH;           // [16384][256] 16 MB

    transpose_x_kernel<<<dim3(IN_DIM / 64, BATCH / 64), 256, 0, stream>>>(x, xT);
    dendrite_kernel<<<N_SOMA, 256, 0, stream>>>(dW, db, xT, dendT);
    soma_kernel<<<dim3(N_NEURONS / 16, BATCH / 64), 256, 0, stream>>>(sW, sb, dendT, out);
}

// Round 2
// 83.146 us; speedup vs baseline: 1.0520x; 1.0520x over previous
//
#include <hip/hip_runtime.h>

#define IN_DIM 4096
#define N_SOMA 16384
#define N_NEURONS 1024
#define BATCH 256
#define NEG_SLOPE 0.1f

typedef float f32x4 __attribute__((ext_vector_type(4)));

// ---------------------------------------------------------------------------
// Kernel 1: transpose x [BATCH][IN_DIM] -> xT [IN_DIM][BATCH]
// ---------------------------------------------------------------------------
__global__ __launch_bounds__(256) void transpose_x_kernel(
    const float* __restrict__ x, float* __restrict__ xT) {
    __shared__ float tile[64][65];
    const int i0 = blockIdx.x * 64;
    const int b0 = blockIdx.y * 64;
    const int lane = threadIdx.x & 63;
    const int grp  = threadIdx.x >> 6;

#pragma unroll
    for (int r = 0; r < 16; ++r) {
        const int b_local = grp * 16 + r;
        tile[b_local][lane] = x[(size_t)(b0 + b_local) * IN_DIM + i0 + lane];
    }
    __syncthreads();
#pragma unroll
    for (int r = 0; r < 16; ++r) {
        const int i_local = grp * 16 + r;
        xT[(size_t)(i0 + i_local) * BATCH + b0 + lane] = tile[lane][i_local];
    }
}

// ---------------------------------------------------------------------------
// Kernel 2: pure-streaming sparse compaction.
// One wave per soma row: 16 float4 nontemporal loads (1 KB in flight per
// wave), ballot/popcount compaction in index order (deterministic, no
// barriers, no LDS), scatter (idx, w) pairs to cIdx/cW [N_SOMA][32].
// ---------------------------------------------------------------------------
__global__ __launch_bounds__(256) void compact_kernel(
    const float* __restrict__ W, int* __restrict__ cIdx, float* __restrict__ cW) {
    const int wave = threadIdx.x >> 6;
    const int lane = threadIdx.x & 63;
    const int d = blockIdx.x * 4 + wave;

    const f32x4* row4 = reinterpret_cast<const f32x4*>(W + (size_t)d * IN_DIM);
    f32x4 v[16];
#pragma unroll
    for (int k = 0; k < 16; ++k) {
        v[k] = __builtin_nontemporal_load(row4 + k * 64 + lane);
    }

    const unsigned long long lt = (1ull << lane) - 1ull;  // lanes below me
    int* __restrict__ rowIdx = cIdx + (size_t)d * 32;
    float* __restrict__ rowW = cW + (size_t)d * 32;

    int base = 0;
#pragma unroll
    for (int k = 0; k < 16; ++k) {
        float e[4] = {v[k].x, v[k].y, v[k].z, v[k].w};
        unsigned long long m[4];
#pragma unroll
        for (int c = 0; c < 4; ++c) m[c] = __ballot(e[c] != 0.f);

        // elements ordered by global index = ((k*64+lane)*4 + c): lane-major,
        // then component. rank = nonzeros at lower lanes (all comps) +
        // nonzeros at earlier comps of my lane.
        int below = 0;
#pragma unroll
        for (int c = 0; c < 4; ++c) below += __popcll(m[c] & lt);

        int myprev = 0;
#pragma unroll
        for (int c = 0; c < 4; ++c) {
            if (e[c] != 0.f) {
                const int pos = base + below + myprev;
                if (pos < 32) {
                    rowIdx[pos] = ((k * 64 + lane) << 2) + c;
                    rowW[pos] = e[c];
                }
                ++myprev;
            }
        }
#pragma unroll
        for (int c = 0; c < 4; ++c) base += __popcll(m[c]);
    }
}

// ---------------------------------------------------------------------------
// Kernel 3: fused sparse dendrite + LeakyReLU + block-diagonal soma +
// LeakyReLU. One block per neuron (16 dendrites x 32 pairs in LDS),
// thread = batch column. Inner loops compile-time bound -> fully unrolled,
// 32 independent coalesced 256B gathers from L2-resident xT in flight.
// ---------------------------------------------------------------------------
__global__ __launch_bounds__(256) void neuron_kernel(
    const int* __restrict__ cIdx, const float* __restrict__ cW,
    const float* __restrict__ db, const float* __restrict__ sW,
    const float* __restrict__ sb, const float* __restrict__ xT,
    float* __restrict__ out) {
    // XCD-chunked swizzle: consecutive neurons on the same XCD so the strided
    // out[b][n] column writes merge into full cache lines in one L2.
    const int bid = blockIdx.x;
    const int n = (bid & 7) * (N_NEURONS / 8) + (bid >> 3);
    const int t = threadIdx.x;  // batch column

    __shared__ int   s_idx[512];
    __shared__ float s_w[512];
    __shared__ float s_sw[16];
    __shared__ float s_db[16];

    {
        const int* gi = cIdx + (size_t)n * 512;
        const float* gw = cW + (size_t)n * 512;
        s_idx[t]       = gi[t] << 8;        // pre-scale: idx * BATCH
        s_idx[t + 256] = gi[t + 256] << 8;
        s_w[t]         = gw[t];
        s_w[t + 256]   = gw[t + 256];
    }
    if (t < 16) {
        s_sw[t] = sW[(size_t)n * N_SOMA + n * 16 + t];
        s_db[t] = db[n * 16 + t];
    }
    __syncthreads();

    float sacc = sb[n];
#pragma unroll
    for (int r = 0; r < 16; ++r) {
        float dacc = s_db[r];
#pragma unroll
        for (int j = 0; j < 32; ++j) {
            dacc = fmaf(s_w[r * 32 + j], xT[(size_t)s_idx[r * 32 + j] + t], dacc);
        }
        dacc = (dacc >= 0.f) ? dacc : NEG_SLOPE * dacc;
        sacc = fmaf(s_sw[r], dacc, sacc);
    }
    sacc = (sacc >= 0.f) ? sacc : NEG_SLOPE * sacc;
    out[(size_t)t * N_NEURONS + n] = sacc;
}

// ---------------------------------------------------------------------------
extern "C" void kernel_launch(void* const* d_in, const int* in_sizes, int n_in,
                              void* d_out, int out_size, void* d_ws, size_t ws_size,
                              hipStream_t stream) {
    const float* x  = (const float*)d_in[0];  // [256][4096]
    const float* dW = (const float*)d_in[1];  // [16384][4096] (pre-masked)
    const float* db = (const float*)d_in[2];  // [16384]
    const float* sW = (const float*)d_in[3];  // [1024][16384] (pre-masked)
    const float* sb = (const float*)d_in[4];  // [1024]
    float* out = (float*)d_out;               // [256][1024]

    float* xT   = (float*)d_ws;                     // [4096][256]   4 MB
    int*   cIdx = (int*)(xT + (size_t)IN_DIM * BATCH);   // [16384][32] 2 MB
    float* cW   = (float*)(cIdx + (size_t)N_SOMA * 32);  // [16384][32] 2 MB

    transpose_x_kernel<<<dim3(IN_DIM / 64, BATCH / 64), 256, 0, stream>>>(x, xT);
    compact_kernel<<<N_SOMA / 4, 256, 0, stream>>>(dW, cIdx, cW);
    neuron_kernel<<<N_NEURONS, 256, 0, stream>>>(cIdx, cW, db, sW, sb, xT, out);
}